// Round 5
// baseline (496.981 us; speedup 1.0000x reference)
//
#include <hip/hip_runtime.h>
#include <cmath>

#define T_TOK 8192
#define N_EXP 256
#define HID   7168
#define NCH   896     // HID/8 chunks of 8 elements
#define KZ    8       // main-GEMM k-split
#define KCH   896     // k-floats per split (HID/KZ)
#define KR    896     // rescue k-split chunk
#define RESCUE_CAP 2048
#define MTAU 4e-5     // expert-chain margin threshold (score space), ~3x the 5-sigma bf16-split error
#define GTAU 1.6e-4   // group-sum margin threshold (= 4*MTAU)

typedef unsigned short u16;
typedef short bf16x8 __attribute__((ext_vector_type(8)));
typedef float f32x4 __attribute__((ext_vector_type(4)));
typedef float f32x16 __attribute__((ext_vector_type(16)));
typedef double f64x4 __attribute__((ext_vector_type(4)));

__device__ __forceinline__ u16 bf16_rtne(float f) {
    unsigned u = __float_as_uint(f);
    u += 0x7FFFu + ((u >> 16) & 1u);
    return (u16)(u >> 16);
}
__device__ __forceinline__ float bf16_f(u16 h) { return __uint_as_float(((unsigned)h) << 16); }

// fp32 -> (hi,lo) bf16 pair via native __bf16 casts (RTNE, bit-identical to
// the manual twiddle for finite inputs)
__device__ __forceinline__ void cvt8(float4 a, float4 b, bf16x8& H, bf16x8& L) {
    const float f[8] = {a.x, a.y, a.z, a.w, b.x, b.y, b.z, b.w};
#pragma unroll
    for (int i = 0; i < 8; ++i) {
        const __bf16 h = (__bf16)f[i];
        const u16 hb = __builtin_bit_cast(u16, h);
        H[i] = (short)hb;
        const float hif = __uint_as_float(((unsigned)hb) << 16);
        const __bf16 l = (__bf16)(f[i] - hif);
        L[i] = (short)__builtin_bit_cast(u16, l);
    }
}

// LDS x-tile [rows][32 bf16], per-row XOR swizzle of the 16B chunk index.
// 8 distinct b128 slots per 8 rows -> 4-way on 32-row column reads (floor for
// 64B rows; structural minimum for aligned b128).
__device__ __forceinline__ int swz(int row, int c16) {
    return row * 32 + (((c16 ^ (row >> 1)) & 3) << 3);
}

__global__ __launch_bounds__(256)
void zero_logits(float* __restrict__ p, int* __restrict__ cnt) {
    if (blockIdx.x == 0 && threadIdx.x == 0) *cnt = 0;
    const size_t i = ((size_t)blockIdx.x * 256 + threadIdx.x) * 4;
    *(float4*)(p + i) = make_float4(0.f, 0.f, 0.f, 0.f);
}

__global__ __launch_bounds__(256)
void zero_resc(float4* __restrict__ p) {
    p[(size_t)blockIdx.x * 256 + threadIdx.x] = make_float4(0.f, 0.f, 0.f, 0.f);
}

// ---------------------------------------------------------------------------
// K1 v2: split w fp32 -> (wh, wl) bf16 pair in FRAGMENT-MAJOR layout:
//   out[((rb*NCH + c)*32 + r5)*8 + j] = split(w[rb*32+r5][c*8+j])
// so a wave's B-fragment load (lane la32 -> row rb*32+la32, chunk c) is one
// fully-coalesced 16B/lane global load (1 KB/wave-instr, contiguous).
// ---------------------------------------------------------------------------
__global__ __launch_bounds__(256)
void wsplit_frag(const float* __restrict__ w, u16* __restrict__ whf, u16* __restrict__ wlf)
{
    const int tid = threadIdx.x;
    const int r5 = tid & 31, c_lo = tid >> 5;            // 0..31, 0..7
    const int rb = blockIdx.x / 112, c_hi = blockIdx.x % 112;
    const int c = c_hi * 8 + c_lo;                       // 0..895
    const int row = rb * 32 + r5;
    const float* src = w + (size_t)row * HID + c * 8;
    const float4 f0 = *(const float4*)src;
    const float4 f1 = *(const float4*)(src + 4);
    const float f[8] = {f0.x, f0.y, f0.z, f0.w, f1.x, f1.y, f1.z, f1.w};
    bf16x8 H, L;
#pragma unroll
    for (int i = 0; i < 8; ++i) {
        const u16 h = bf16_rtne(f[i]);
        H[i] = (short)h;
        L[i] = (short)bf16_rtne(f[i] - bf16_f(h));
    }
    const size_t out = ((size_t)(rb * NCH + c) * 32 + r5) * 8;
    *(bf16x8*)(whf + out) = H;
    *(bf16x8*)(wlf + out) = L;
}

// ---------------------------------------------------------------------------
// K2 v12: w-fragments from REGISTERS (L2-resident, fragment-major layout);
// LDS holds only x (32 KB) -> 3 blocks/CU (__launch_bounds__(256,3)).
//  - Removes global_load_lds entirely: at each barrier all outstanding loads
//    are already consumed -> the vmcnt(0) drain is free; cross-block TLP
//    (3 blocks staggered) hides the remaining per-iter latency.
//  - BM=128 x BN=128, BK=32, 4 waves, wave tile 64x64; K-split x8 -> grid
//    1024. 28 k-steps/block. B loads per ksub (32 VGPR live) keep pressure
//    under the 170 cap.
//  - atomicAdd combine: 8 contributions/cell on zeroed logits; fp32
//    order-noise ~1e-7 in score space, 400x below MTAU.
// ---------------------------------------------------------------------------
__global__ __launch_bounds__(256, 3)
void gemm_bf16split_v12(const float* __restrict__ x, const u16* __restrict__ whf,
                        const u16* __restrict__ wlf, float* __restrict__ logits)
{
    __shared__ u16 sxh[2][128 * 32], sxl[2][128 * 32];   // 32 KiB
    const int tid = threadIdx.x;
    const int wave = tid >> 6, lane = tid & 63;

    // mapping: h[2:0]=slab_lo (XCD lane), h[6:3]=(col,kz), h[9:7]=slab_hi
    const int h = blockIdx.x;
    const int cc = (h >> 3) & 15;
    const int col = cc & 1, kz = cc >> 1;      // 2 expert cols x 8 k-splits
    const int slab = (h & 7) | ((h >> 7) << 3);
    const int t0 = slab * 128;
    const int kbase = kz * KCH;
    const int kc0 = kz * (KCH / 8);            // chunk base

    const int la32 = lane & 31, ksel = lane >> 5;

    // calibration probes: decode 32x32 C/D reg->(row,col) on-device (proven)
    bf16x8 pidx = (bf16x8)(short)0, pone = (bf16x8)(short)0;
    if (ksel == 0) {
        pidx[0] = (short)bf16_rtne((float)la32);
        pone[0] = (short)0x3F80;
    }
    f32x16 pr = __builtin_amdgcn_mfma_f32_32x32x16_bf16(pidx, pone, (f32x16)(0.f), 0, 0, 0);
    f32x16 pc = __builtin_amdgcn_mfma_f32_32x32x16_bf16(pone, pidx, (f32x16)(0.f), 0, 0, 0);
    int rrow[16], rcol[16];
#pragma unroll
    for (int i = 0; i < 16; ++i) {
        rrow[i] = (int)(pr[i] + 0.5f);
        rcol[i] = (int)(pc[i] + 0.5f);
    }

    // x staging: thread -> row sr (0..127), k-half halfk (16 floats)
    const int sr = tid >> 1, halfk = tid & 1;
    const float* xp = x + (size_t)(t0 + sr) * HID + kbase + halfk * 16;

    // B-fragment pointers (fragment-major): wave owns row-blocks rb0, rb0+1
    const int rb0 = col * 4 + (wave & 1) * 2;
    const size_t lb = (size_t)la32 * 8;
    const u16* bh0 = whf + ((size_t)rb0 * NCH + kc0 + ksel) * 256 + lb;
    const u16* bh1 = whf + ((size_t)(rb0 + 1) * NCH + kc0 + ksel) * 256 + lb;
    const u16* bl0 = wlf + ((size_t)rb0 * NCH + kc0 + ksel) * 256 + lb;
    const u16* bl1 = wlf + ((size_t)(rb0 + 1) * NCH + kc0 + ksel) * 256 + lb;

    f32x16 acc[2][2];
#pragma unroll
    for (int i = 0; i < 2; ++i)
#pragma unroll
        for (int j = 0; j < 2; ++j) acc[i][j] = (f32x16)(0.f);

    const int m0 = (wave >> 1) * 64;

    // ---- prologue: stage x tile 0 into buffer 0 ----
    {
        float4 a = *(const float4*)xp,       b = *(const float4*)(xp + 4);
        float4 c = *(const float4*)(xp + 8), d = *(const float4*)(xp + 12);
        bf16x8 XH0, XH1, XL0, XL1;
        cvt8(a, b, XH0, XL0);
        cvt8(c, d, XH1, XL1);
        *(bf16x8*)&sxh[0][swz(sr, 2 * halfk)]     = XH0;
        *(bf16x8*)&sxh[0][swz(sr, 2 * halfk + 1)] = XH1;
        *(bf16x8*)&sxl[0][swz(sr, 2 * halfk)]     = XL0;
        *(bf16x8*)&sxl[0][swz(sr, 2 * halfk + 1)] = XL1;
    }
    __syncthreads();

    int cur = 0;
    for (int k0 = 0; k0 < KCH; k0 += 32) {
        const int nxt = cur ^ 1;
        const bool more = (k0 + 32 < KCH);
        const int bo = k0 * 32;                 // u16 offset: (k0/8)*256

        // --- B loads ksub0 (chunk ksel) + next-x loads: issued first
        bf16x8 B0h[2], B0l[2];
        B0h[0] = *(const bf16x8*)(bh0 + bo);
        B0h[1] = *(const bf16x8*)(bh1 + bo);
        B0l[0] = *(const bf16x8*)(bl0 + bo);
        B0l[1] = *(const bf16x8*)(bl1 + bo);
        float4 xa, xb, xc, xd;
        if (more) {
            const float* p = xp + k0 + 32;
            xa = *(const float4*)p;       xb = *(const float4*)(p + 4);
            xc = *(const float4*)(p + 8); xd = *(const float4*)(p + 12);
        }
        // --- A reads + MFMA ksub0
        {
            bf16x8 Ah[2], Al[2];
#pragma unroll
            for (int mi = 0; mi < 2; ++mi) {
                const int r = m0 + 32 * mi + la32;
                Ah[mi] = *(const bf16x8*)&sxh[cur][swz(r, ksel)];
                Al[mi] = *(const bf16x8*)&sxl[cur][swz(r, ksel)];
            }
#pragma unroll
            for (int mi = 0; mi < 2; ++mi)
#pragma unroll
                for (int ni = 0; ni < 2; ++ni) {
                    acc[mi][ni] = __builtin_amdgcn_mfma_f32_32x32x16_bf16(Ah[mi], B0h[ni], acc[mi][ni], 0, 0, 0);
                    acc[mi][ni] = __builtin_amdgcn_mfma_f32_32x32x16_bf16(Ah[mi], B0l[ni], acc[mi][ni], 0, 0, 0);
                    acc[mi][ni] = __builtin_amdgcn_mfma_f32_32x32x16_bf16(Al[mi], B0h[ni], acc[mi][ni], 0, 0, 0);
                }
        }
        // --- B loads ksub1 (chunk 2+ksel), then A reads + MFMA ksub1
        {
            bf16x8 B1h[2], B1l[2];
            B1h[0] = *(const bf16x8*)(bh0 + bo + 512);
            B1h[1] = *(const bf16x8*)(bh1 + bo + 512);
            B1l[0] = *(const bf16x8*)(bl0 + bo + 512);
            B1l[1] = *(const bf16x8*)(bl1 + bo + 512);
            bf16x8 Ah[2], Al[2];
#pragma unroll
            for (int mi = 0; mi < 2; ++mi) {
                const int r = m0 + 32 * mi + la32;
                Ah[mi] = *(const bf16x8*)&sxh[cur][swz(r, 2 + ksel)];
                Al[mi] = *(const bf16x8*)&sxl[cur][swz(r, 2 + ksel)];
            }
#pragma unroll
            for (int mi = 0; mi < 2; ++mi)
#pragma unroll
                for (int ni = 0; ni < 2; ++ni) {
                    acc[mi][ni] = __builtin_amdgcn_mfma_f32_32x32x16_bf16(Ah[mi], B1h[ni], acc[mi][ni], 0, 0, 0);
                    acc[mi][ni] = __builtin_amdgcn_mfma_f32_32x32x16_bf16(Ah[mi], B1l[ni], acc[mi][ni], 0, 0, 0);
                    acc[mi][ni] = __builtin_amdgcn_mfma_f32_32x32x16_bf16(Al[mi], B1h[ni], acc[mi][ni], 0, 0, 0);
                }
        }
        // --- late: convert + stage next x tile
        if (more) {
            bf16x8 XH0, XH1, XL0, XL1;
            cvt8(xa, xb, XH0, XL0);
            cvt8(xc, xd, XH1, XL1);
            *(bf16x8*)&sxh[nxt][swz(sr, 2 * halfk)]     = XH0;
            *(bf16x8*)&sxh[nxt][swz(sr, 2 * halfk + 1)] = XH1;
            *(bf16x8*)&sxl[nxt][swz(sr, 2 * halfk)]     = XL0;
            *(bf16x8*)&sxl[nxt][swz(sr, 2 * halfk + 1)] = XL1;
        }
        __syncthreads();   // all loads already consumed -> drain is ~free
        cur = nxt;
    }

    // k-split combine: 8 contributions per cell onto zeroed memory.
#pragma unroll
    for (int mi = 0; mi < 2; ++mi)
#pragma unroll
        for (int ni = 0; ni < 2; ++ni)
#pragma unroll
            for (int i = 0; i < 16; ++i)
                atomicAdd(&logits[(size_t)(t0 + m0 + 32 * mi + rrow[i]) * N_EXP + (rb0 + ni) * 32 + rcol[i]],
                          acc[mi][ni][i]);
}

// ---------------------------------------------------------------------------
// K3 v2: routing + margin flags in FP32. The fp64 version was ~2.1M software
// double-exp (~120us VALU). fp32 sigmoid error ~1e-7 << MTAU=4e-5: any
// decision fp32 could get wrong has margin < MTAU -> flagged -> fp64 rescue
// recomputes it. Structure/semantics otherwise identical to the proven r7 code.
// ---------------------------------------------------------------------------
__global__ __launch_bounds__(256)
void route_flag(const float* __restrict__ logits, const float* __restrict__ bias,
                float* __restrict__ out_idx, float* __restrict__ out_w,
                int* __restrict__ cnt, int* __restrict__ list)
{
    const int wave = threadIdx.x >> 6;
    const int lane = threadIdx.x & 63;
    const int t = blockIdx.x * 4 + wave;

    const float4 lg = *(const float4*)(logits + (size_t)t * N_EXP + 4 * lane);
    const float4 bf = *(const float4*)(bias + 4 * lane);
    const float lgv[4] = {lg.x, lg.y, lg.z, lg.w};
    const float bfv[4] = {bf.x, bf.y, bf.z, bf.w};
    float raw[4], v[4];
#pragma unroll
    for (int j = 0; j < 4; ++j) {
        raw[j] = 1.0f / (1.0f + expf(-lgv[j]));
        v[j] = raw[j] + bfv[j];
    }

    float m1 = -1e30f, m2 = -1e30f;
#pragma unroll
    for (int j = 0; j < 4; ++j) {
        if (v[j] > m1) { m2 = m1; m1 = v[j]; }
        else if (v[j] > m2) { m2 = v[j]; }
    }
#pragma unroll
    for (int d = 1; d <= 4; d <<= 1) {
        const float o1 = __shfl_xor(m1, d);
        const float o2 = __shfl_xor(m2, d);
        if (o1 > m1) { m2 = fmaxf(m1, o2); m1 = o1; }
        else         { m2 = fmaxf(m2, o1); }
    }
    const float gsum = m1 + m2;

    float gq[8];
#pragma unroll
    for (int g = 0; g < 8; ++g) gq[g] = __shfl(gsum, g * 8);
    int gm = 0;
    float g4v = -1e30f, gmargin = 1e30f;
#pragma unroll
    for (int rr = 0; rr < 5; ++rr) {
        int best = 0; float bv = -1e30f;
#pragma unroll
        for (int g = 0; g < 8; ++g) {
            const bool taken = (gm >> g) & 1;
            if (!taken && gq[g] > bv) { bv = gq[g]; best = g; }
        }
        if (rr < 4) { gm |= (1 << best); g4v = bv; }
        else gmargin = g4v - bv;
    }

    float cv[4];
    const bool inmask = (gm >> (lane >> 3)) & 1;
#pragma unroll
    for (int j = 0; j < 4; ++j) cv[j] = inmask ? v[j] : 0.0f;

    float wsum = 0.0f, my_w = 0.0f, prev = 0.0f, mmin = 1e30f;
    int my_i = 0;
#pragma unroll
    for (int rr = 0; rr < 9; ++rr) {
        float bv = cv[0]; int bj = 0;
#pragma unroll
        for (int j = 1; j < 4; ++j)
            if (cv[j] > bv) { bv = cv[j]; bj = j; }
        int bi = 4 * lane + bj;
        float braw = (bj == 0) ? raw[0] : (bj == 1) ? raw[1] : (bj == 2) ? raw[2] : raw[3];
#pragma unroll
        for (int d = 1; d < 64; d <<= 1) {
            const float ov  = __shfl_xor(bv, d);
            const int   oi  = __shfl_xor(bi, d);
            const float orw = __shfl_xor(braw, d);
            if (ov > bv || (ov == bv && oi < bi)) { bv = ov; bi = oi; braw = orw; }
        }
        if (rr > 0) mmin = fminf(mmin, prev - bv);
        prev = bv;
        if (rr < 8) {
            wsum += braw;
            if (lane == rr) { my_i = bi; my_w = braw; }
            if ((bi >> 2) == lane) cv[bi & 3] = -1e30f;
        }
    }

    const float scale = 2.5f / (wsum + 1e-20f);
    if (lane < 8) {
        out_idx[(size_t)t * 8 + lane] = (float)my_i;
        out_w [(size_t)t * 8 + lane] = my_w * scale;
    }
    const bool flag = (mmin < (float)MTAU) || (gmargin < (float)GTAU);
    if (flag && lane == 0) {
        const int idx = atomicAdd(cnt, 1);
        if (idx < RESCUE_CAP) list[idx] = t;
    }
}

// ---------------------------------------------------------------------------
// K4 v9: fp64 rescue GEMM, K-split x8 + single-barrier dbuf (round-4 proven).
// ---------------------------------------------------------------------------
__global__ __launch_bounds__(256, 2)
void rescue_gemm64_v9(const float* __restrict__ x, const float* __restrict__ w,
                      const int* __restrict__ cnt, const int* __restrict__ list,
                      double* __restrict__ resc /* [RESCUE_CAP][N_EXP] raw logits */)
{
    const int nf = min(*cnt, RESCUE_CAP);
    const int t0 = blockIdx.y * 32;
    if (t0 >= nf) return;

    __shared__ double xs[2][32][33];
    __shared__ double wsh[2][32][33];
    const int tid  = threadIdx.x;
    const int wave = tid >> 6;
    const int lane = tid & 63;
    const int e0 = blockIdx.x * 32;
    const int kbase = blockIdx.z * KR;
    const int la = lane & 15;
    const int kq = lane >> 4;

    const double p_idx = (kq == 0) ? (double)la : 0.0;
    const double p_one = (kq == 0) ? 1.0 : 0.0;
    f64x4 prow = (f64x4)(0.0), pcol = (f64x4)(0.0);
    prow = __builtin_amdgcn_mfma_f64_16x16x4f64(p_idx, p_one, prow, 0, 0, 0);
    pcol = __builtin_amdgcn_mfma_f64_16x16x4f64(p_one, p_idx, pcol, 0, 0, 0);
    int rrow[4], rcol[4];
#pragma unroll
    for (int i = 0; i < 4; ++i) {
        rrow[i] = (int)(prow[i] + 0.5);
        rcol[i] = (int)(pcol[i] + 0.5);
    }

    const int r = tid >> 3;     // 0..31
    const int q = tid & 7;
    const int tr = list[min(t0 + r, nf - 1)];
    const float* xp = x + (size_t)tr * HID + kbase + q * 4;
    const float* wp = w + (size_t)(e0 + r) * HID + kbase + q * 4;

    f64x4 acc = (f64x4)(0.0);
    const int m0 = (wave & 1) * 16;
    const int n0 = (wave >> 1) * 16;

    {
        const float4 xv = *(const float4*)xp;
        const float4 wv = *(const float4*)wp;
        const float a[4] = {xv.x, xv.y, xv.z, xv.w};
        const float b[4] = {wv.x, wv.y, wv.z, wv.w};
#pragma unroll
        for (int j = 0; j < 4; ++j) {
            xs[0][4 * q + j][r]  = (double)a[j];
            wsh[0][4 * q + j][r] = (double)b[j];
        }
    }
    __syncthreads();

    int cur = 0;
    for (int k0 = 0; k0 < KR; k0 += 32) {
        const int nxt = cur ^ 1;
        const bool more = (k0 + 32 < KR);
        float4 xv, wv;
        if (more) {
            xv = *(const float4*)(xp + k0 + 32);
            wv = *(const float4*)(wp + k0 + 32);
        }
#pragma unroll
        for (int s = 0; s < 8; ++s) {
            const int kk = s * 4 + kq;
            const double a = xs[cur][kk][m0 + la];
            const double b = wsh[cur][kk][n0 + la];
            acc = __builtin_amdgcn_mfma_f64_16x16x4f64(a, b, acc, 0, 0, 0);
        }
        if (more) {
            const float a[4] = {xv.x, xv.y, xv.z, xv.w};
            const float b[4] = {wv.x, wv.y, wv.z, wv.w};
#pragma unroll
            for (int j = 0; j < 4; ++j) {
                xs[nxt][4 * q + j][r]  = (double)a[j];
                wsh[nxt][4 * q + j][r] = (double)b[j];
            }
        }
        __syncthreads();
        cur = nxt;
    }

#pragma unroll
    for (int i = 0; i < 4; ++i) {
        const size_t lt = t0 + m0 + rrow[i];
        atomicAdd(&resc[lt * N_EXP + e0 + n0 + rcol[i]], acc[i]);
    }
}

// ---------------------------------------------------------------------------
// K5: fp64 rescue routing (sigmoid applied here; round-4 proven).
// ---------------------------------------------------------------------------
__global__ __launch_bounds__(256)
void rescue_route(const double* __restrict__ resc, const float* __restrict__ bias,
                  const int* __restrict__ cnt, const int* __restrict__ list,
                  float* __restrict__ out_idx, float* __restrict__ out_w)
{
    const int nf = min(*cnt, RESCUE_CAP);
    const int wave = threadIdx.x >> 6;
    const int lane = threadIdx.x & 63;
    const int i_tok = blockIdx.x * 4 + wave;
    if (i_tok >= nf) return;
    const int t = list[i_tok];
    const double* srow = resc + (size_t)i_tok * N_EXP;

    const float4 bf = *(const float4*)(bias + lane * 4);
    const float bfv[4] = {bf.x, bf.y, bf.z, bf.w};
    double raw[4], v[4];
#pragma unroll
    for (int j = 0; j < 4; ++j) {
        raw[j] = 1.0 / (1.0 + exp(-srow[4 * lane + j]));
        v[j] = raw[j] + (double)bfv[j];
    }

    double m1 = -1e300, m2 = -1e300;
#pragma unroll
    for (int j = 0; j < 4; ++j) {
        if (v[j] > m1) { m2 = m1; m1 = v[j]; }
        else if (v[j] > m2) { m2 = v[j]; }
    }
#pragma unroll
    for (int d = 1; d <= 4; d <<= 1) {
        const double o1 = __shfl_xor(m1, d);
        const double o2 = __shfl_xor(m2, d);
        if (o1 > m1) { m2 = fmax(m1, o2); m1 = o1; }
        else         { m2 = fmax(m2, o1); }
    }
    const double gsum = m1 + m2;

    double gq[8];
#pragma unroll
    for (int g = 0; g < 8; ++g) gq[g] = __shfl(gsum, g * 8);
    int gm = 0;
#pragma unroll
    for (int rr = 0; rr < 4; ++rr) {
        int best = 0; double bv = -1e300;
#pragma unroll
        for (int g = 0; g < 8; ++g) {
            const bool taken = (gm >> g) & 1;
            if (!taken && gq[g] > bv) { bv = gq[g]; best = g; }
        }
        gm |= (1 << best);
    }

    double cv[4];
    const bool inmask = (gm >> (lane >> 3)) & 1;
#pragma unroll
    for (int j = 0; j < 4; ++j) cv[j] = inmask ? v[j] : 0.0;

    double wsum = 0.0, my_w = 0.0;
    int my_i = 0;
#pragma unroll
    for (int rr = 0; rr < 8; ++rr) {
        double bv = cv[0]; int bj = 0;
#pragma unroll
        for (int j = 1; j < 4; ++j)
            if (cv[j] > bv) { bv = cv[j]; bj = j; }
        int bi = 4 * lane + bj;
        double braw = (bj == 0) ? raw[0] : (bj == 1) ? raw[1] : (bj == 2) ? raw[2] : raw[3];
#pragma unroll
        for (int d = 1; d < 64; d <<= 1) {
            const double ov  = __shfl_xor(bv, d);
            const int    oi  = __shfl_xor(bi, d);
            const double orw = __shfl_xor(braw, d);
            if (ov > bv || (ov == bv && oi < bi)) { bv = ov; bi = oi; braw = orw; }
        }
        wsum += braw;
        if (lane == rr) { my_i = bi; my_w = braw; }
        if ((bi >> 2) == lane) cv[bi & 3] = -1e300;
    }

    const double scale = 2.5 / (wsum + 1e-20);
    if (lane < 8) {
        out_idx[(size_t)t * 8 + lane] = (float)my_i;
        out_w [(size_t)t * 8 + lane] = (float)(my_w * scale);
    }
}

extern "C" void kernel_launch(void* const* d_in, const int* in_sizes, int n_in,
                              void* d_out, int out_size, void* d_ws, size_t ws_size,
                              hipStream_t stream)
{
    const float* x    = (const float*)d_in[0];
    const float* w    = (const float*)d_in[1];
    const float* bias = (const float*)d_in[2];
    float* out = (float*)d_out;

    char* ws = (char*)d_ws;
    float*  logits = (float*)ws;                       // 8,388,608 B
    double* resc   = (double*)ws;                      // alias: logits dead after route_flag
    u16*    whf    = (u16*)(ws + 8388608);             // 3,670,016 B (fragment-major)
    u16*    wlf    = (u16*)(ws + 12058624);            // 3,670,016 B
    int*    cnt    = (int*)(ws + 15728640);
    int*    list   = (int*)(ws + 15728704);            // 2048*4

    zero_logits<<<(T_TOK * N_EXP) / (256 * 4), 256, 0, stream>>>(logits, cnt);
    wsplit_frag<<<8 * 112, 256, 0, stream>>>(w, whf, wlf);
    gemm_bf16split_v12<<<1024, 256, 0, stream>>>(x, whf, wlf, logits);
    route_flag<<<T_TOK / 4, 256, 0, stream>>>(logits, bias, out, out + (size_t)T_TOK * 8, cnt, list);
    // resc aliases logits -> zero AFTER route_flag consumed logits
    zero_resc<<<(RESCUE_CAP * N_EXP * 8) / (16 * 256), 256, 0, stream>>>((float4*)resc);
    rescue_gemm64_v9<<<dim3(N_EXP / 32, RESCUE_CAP / 32, HID / KR), 256, 0, stream>>>(x, w, cnt, list, resc);
    rescue_route<<<RESCUE_CAP / 4, 256, 0, stream>>>(resc, bias, cnt, list, out, out + (size_t)T_TOK * 8);
}

// Round 6
// 458.213 us; speedup vs baseline: 1.0846x; 1.0846x over previous
//
#include <hip/hip_runtime.h>
#include <cmath>

#define T_TOK 8192
#define N_EXP 256
#define HID   7168
#define KQUART 1792
#define KR    896     // rescue k-split chunk
#define RESCUE_CAP 2048
#define MTAU 4e-5     // expert-chain margin threshold (score space), ~3x the 5-sigma bf16-split error
#define GTAU 1.6e-4   // group-sum margin threshold (= 4*MTAU)

typedef unsigned short u16;
typedef short bf16x8 __attribute__((ext_vector_type(8)));
typedef float f32x4 __attribute__((ext_vector_type(4)));
typedef float f32x16 __attribute__((ext_vector_type(16)));
typedef double f64x4 __attribute__((ext_vector_type(4)));

typedef const __attribute__((address_space(1))) unsigned int* gas_ptr;
typedef __attribute__((address_space(3))) unsigned int* las_ptr;

__device__ __forceinline__ u16 bf16_rtne(float f) {
    unsigned u = __float_as_uint(f);
    u += 0x7FFFu + ((u >> 16) & 1u);
    return (u16)(u >> 16);
}
__device__ __forceinline__ float bf16_f(u16 h) { return __uint_as_float(((unsigned)h) << 16); }

// fp32 -> (hi,lo) bf16 pair via native __bf16 casts (RTNE, bit-identical to
// the manual twiddle for finite inputs)
__device__ __forceinline__ void cvt8(float4 a, float4 b, bf16x8& H, bf16x8& L) {
    const float f[8] = {a.x, a.y, a.z, a.w, b.x, b.y, b.z, b.w};
#pragma unroll
    for (int i = 0; i < 8; ++i) {
        const __bf16 h = (__bf16)f[i];
        const u16 hb = __builtin_bit_cast(u16, h);
        H[i] = (short)hb;
        const float hif = __uint_as_float(((unsigned)hb) << 16);
        const __bf16 l = (__bf16)(f[i] - hif);
        L[i] = (short)__builtin_bit_cast(u16, l);
    }
}

// W LDS tile [rows][32 u16] (64B rows, DMA-linear requirement), chunk-XOR
// swizzle. 4-way on 32-row column b128 reads (structural floor under DMA).
__device__ __forceinline__ int swz(int row, int c16) {
    return row * 32 + (((c16 ^ (row >> 1)) & 3) << 3);
}
// X LDS tile [rows][48 u16] (96B rows, 16B-aligned). Start banks walk
// {0,24,16,8} with row; x 4-chunk swizzle -> 16 distinct 16B slots per 32
// lanes = 2-way = free (m136). X is ds_write-staged so padding is legal.
__device__ __forceinline__ int swzx(int row, int c16) {
    return row * 48 + (((c16 ^ (row >> 1)) & 3) << 3);
}

__device__ __forceinline__ void gload16(const void* g, void* l) {
    __builtin_amdgcn_global_load_lds((gas_ptr)g, (las_ptr)l, 16, 0, 0);
}

__global__ __launch_bounds__(256)
void zero_resc(float4* __restrict__ p) {
    p[(size_t)blockIdx.x * 256 + threadIdx.x] = make_float4(0.f, 0.f, 0.f, 0.f);
}

// ---------------------------------------------------------------------------
// K1 "prep": fused zero_logits + cnt reset + wsplit (saves one launch).
// Blocks 0..895 additionally split w fp32 -> (wh, wl) bf16 pair (row-major,
// exact: wl = bf16(w - float(wh))). All 2048 blocks zero a logits chunk.
// ---------------------------------------------------------------------------
__global__ __launch_bounds__(256)
void prep(const float* __restrict__ w, u16* __restrict__ wh, u16* __restrict__ wl,
          float* __restrict__ logits, int* __restrict__ cnt)
{
    const int tid = threadIdx.x;
    if (blockIdx.x == 0 && tid == 0) *cnt = 0;
    const size_t zi = ((size_t)blockIdx.x * 256 + tid) * 4;
    *(float4*)(logits + zi) = make_float4(0.f, 0.f, 0.f, 0.f);

    if (blockIdx.x < 896) {
        const size_t base = ((size_t)blockIdx.x * 256 + tid) * 8;
        const float4 f0 = *(const float4*)(w + base);
        const float4 f1 = *(const float4*)(w + base + 4);
        const float f[8] = {f0.x, f0.y, f0.z, f0.w, f1.x, f1.y, f1.z, f1.w};
        bf16x8 H, L;
#pragma unroll
        for (int i = 0; i < 8; ++i) {
            const u16 h = bf16_rtne(f[i]);
            H[i] = (short)h;
            L[i] = (short)bf16_rtne(f[i] - bf16_f(h));
        }
        *(bf16x8*)(wh + base) = H;
        *(bf16x8*)(wl + base) = L;
    }
}

// ---------------------------------------------------------------------------
// K2 v13 = v11 (proven 155us) + padded X tiles (stride 48 u16) killing the
// 4-way X-read bank conflicts. W path (global_load_lds, 64B rows) unchanged.
// BM=128 x BN=128, BK=32, 4 waves, wave tile 64x64, K-split x4, XCD slabs,
// single-barrier dbuf pipeline, late cvt, atomicAdd combine (4/cell).
// LDS: X 48KB + W 32KB = 80KB -> 2 blocks/CU.
// ---------------------------------------------------------------------------
__global__ __launch_bounds__(256, 2)
void gemm_bf16split_v13(const float* __restrict__ x, const u16* __restrict__ wh,
                        const u16* __restrict__ wl, float* __restrict__ logits)
{
    __shared__ u16 sxh[2][128 * 48], sxl[2][128 * 48];   // 48 KiB
    __shared__ u16 swh[2][128 * 32], swl[2][128 * 32];   // 32 KiB
    const int tid = threadIdx.x;
    const int wave = tid >> 6, lane = tid & 63;

    // block mapping: h&7 -> slab-group lane (XCD), 8 blocks per slab
    const int h = blockIdx.x;
    const int cc8 = (h >> 3) & 7;
    const int col = cc8 & 1, kq = cc8 >> 1;    // 2 expert cols x 4 k-quarters
    const int slab = (h & 7) | ((h >> 6) << 3);
    const int t0 = slab * 128;
    const int e0 = col * 128;
    const int kbase = kq * KQUART;

    const int la32 = lane & 31, ksel = lane >> 5;

    // calibration probes: decode 32x32 C/D reg->(row,col) on-device (proven)
    bf16x8 pidx = (bf16x8)(short)0, pone = (bf16x8)(short)0;
    if (ksel == 0) {
        pidx[0] = (short)bf16_rtne((float)la32);
        pone[0] = (short)0x3F80;
    }
    f32x16 pr = __builtin_amdgcn_mfma_f32_32x32x16_bf16(pidx, pone, (f32x16)(0.f), 0, 0, 0);
    f32x16 pc = __builtin_amdgcn_mfma_f32_32x32x16_bf16(pone, pidx, (f32x16)(0.f), 0, 0, 0);
    int rrow[16], rcol[16];
#pragma unroll
    for (int i = 0; i < 16; ++i) {
        rrow[i] = (int)(pr[i] + 0.5f);
        rcol[i] = (int)(pc[i] + 0.5f);
    }

    // x staging: thread -> row sr (0..127), k-half halfk (16 floats)
    const int sr = tid >> 1, halfk = tid & 1;
    const float* xp = x + (size_t)(t0 + sr) * HID + kbase + halfk * 16;

    // w staging via global_load_lds: each wave DMAs rows [wave*32, wave*32+32)
    const int R0 = wave * 32;
    const int wrow = R0 + (lane >> 2);
    const int wgc = (lane & 3) ^ ((wrow >> 1) & 3);
    const u16* whp0 = wh + (size_t)(e0 + wrow) * HID + kbase + wgc * 8;
    const u16* wlp0 = wl + (size_t)(e0 + wrow) * HID + kbase + wgc * 8;
    const u16* whp1 = whp0 + (size_t)16 * HID;
    const u16* wlp1 = wlp0 + (size_t)16 * HID;
    const int ldsb0 = R0 * 32, ldsb1 = ldsb0 + 512;

    f32x16 acc[2][2];
#pragma unroll
    for (int i = 0; i < 2; ++i)
#pragma unroll
        for (int j = 0; j < 2; ++j) acc[i][j] = (f32x16)(0.f);

    const int m0 = (wave >> 1) * 64;
    const int n0 = (wave & 1) * 64;

    // ---- prologue: stage tile 0 into buffer 0 ----
    gload16(whp0, &swh[0][ldsb0]);
    gload16(whp1, &swh[0][ldsb1]);
    gload16(wlp0, &swl[0][ldsb0]);
    gload16(wlp1, &swl[0][ldsb1]);
    {
        float4 a = *(const float4*)xp,       b = *(const float4*)(xp + 4);
        float4 c = *(const float4*)(xp + 8), d = *(const float4*)(xp + 12);
        bf16x8 XH0, XH1, XL0, XL1;
        cvt8(a, b, XH0, XL0);
        cvt8(c, d, XH1, XL1);
        *(bf16x8*)&sxh[0][swzx(sr, 2 * halfk)]     = XH0;
        *(bf16x8*)&sxh[0][swzx(sr, 2 * halfk + 1)] = XH1;
        *(bf16x8*)&sxl[0][swzx(sr, 2 * halfk)]     = XL0;
        *(bf16x8*)&sxl[0][swzx(sr, 2 * halfk + 1)] = XL1;
    }
    __syncthreads();

    int cur = 0;
    for (int k0 = 0; k0 < KQUART; k0 += 32) {
        const int nxt = cur ^ 1;
        const bool more = (k0 + 32 < KQUART);
        float4 xa, xb, xc, xd;
        if (more) {
            gload16(whp0 + k0 + 32, &swh[nxt][ldsb0]);
            gload16(whp1 + k0 + 32, &swh[nxt][ldsb1]);
            gload16(wlp0 + k0 + 32, &swl[nxt][ldsb0]);
            gload16(wlp1 + k0 + 32, &swl[nxt][ldsb1]);
            const float* p = xp + k0 + 32;
            xa = *(const float4*)p;       xb = *(const float4*)(p + 4);
            xc = *(const float4*)(p + 8); xd = *(const float4*)(p + 12);
        }
#pragma unroll
        for (int ksub = 0; ksub < 2; ++ksub) {
            const int ch = 2 * ksub + ksel;
            bf16x8 Ah[2], Al[2], Bh[2], Bl[2];
#pragma unroll
            for (int mi = 0; mi < 2; ++mi) {
                const int r = m0 + 32 * mi + la32;
                Ah[mi] = *(const bf16x8*)&sxh[cur][swzx(r, ch)];
                Al[mi] = *(const bf16x8*)&sxl[cur][swzx(r, ch)];
            }
#pragma unroll
            for (int ni = 0; ni < 2; ++ni) {
                const int r = n0 + 32 * ni + la32;
                Bh[ni] = *(const bf16x8*)&swh[cur][swz(r, ch)];
                Bl[ni] = *(const bf16x8*)&swl[cur][swz(r, ch)];
            }
#pragma unroll
            for (int mi = 0; mi < 2; ++mi)
#pragma unroll
                for (int ni = 0; ni < 2; ++ni) {
                    acc[mi][ni] = __builtin_amdgcn_mfma_f32_32x32x16_bf16(Ah[mi], Bh[ni], acc[mi][ni], 0, 0, 0);
                    acc[mi][ni] = __builtin_amdgcn_mfma_f32_32x32x16_bf16(Ah[mi], Bl[ni], acc[mi][ni], 0, 0, 0);
                    acc[mi][ni] = __builtin_amdgcn_mfma_f32_32x32x16_bf16(Al[mi], Bh[ni], acc[mi][ni], 0, 0, 0);
                }
        }
        if (more) {
            bf16x8 XH0, XH1, XL0, XL1;
            cvt8(xa, xb, XH0, XL0);
            cvt8(xc, xd, XH1, XL1);
            *(bf16x8*)&sxh[nxt][swzx(sr, 2 * halfk)]     = XH0;
            *(bf16x8*)&sxh[nxt][swzx(sr, 2 * halfk + 1)] = XH1;
            *(bf16x8*)&sxl[nxt][swzx(sr, 2 * halfk)]     = XL0;
            *(bf16x8*)&sxl[nxt][swzx(sr, 2 * halfk + 1)] = XL1;
        }
        __syncthreads();   // ONE barrier/k-step
        cur = nxt;
    }

    // k-split combine: 4 contributions per cell onto zeroed memory.
#pragma unroll
    for (int mi = 0; mi < 2; ++mi)
#pragma unroll
        for (int ni = 0; ni < 2; ++ni)
#pragma unroll
            for (int i = 0; i < 16; ++i)
                atomicAdd(&logits[(size_t)(t0 + m0 + 32 * mi + rrow[i]) * N_EXP + e0 + n0 + 32 * ni + rcol[i]],
                          acc[mi][ni][i]);
}

// ---------------------------------------------------------------------------
// K3 v2: routing + margin flags in FP32 (round-5 proven; fp32 sigmoid error
// ~1e-7 << MTAU -> ambiguous decisions are flagged and fp64-rescued anyway).
// ---------------------------------------------------------------------------
__global__ __launch_bounds__(256)
void route_flag(const float* __restrict__ logits, const float* __restrict__ bias,
                float* __restrict__ out_idx, float* __restrict__ out_w,
                int* __restrict__ cnt, int* __restrict__ list)
{
    const int wave = threadIdx.x >> 6;
    const int lane = threadIdx.x & 63;
    const int t = blockIdx.x * 4 + wave;

    const float4 lg = *(const float4*)(logits + (size_t)t * N_EXP + 4 * lane);
    const float4 bf = *(const float4*)(bias + 4 * lane);
    const float lgv[4] = {lg.x, lg.y, lg.z, lg.w};
    const float bfv[4] = {bf.x, bf.y, bf.z, bf.w};
    float raw[4], v[4];
#pragma unroll
    for (int j = 0; j < 4; ++j) {
        raw[j] = 1.0f / (1.0f + expf(-lgv[j]));
        v[j] = raw[j] + bfv[j];
    }

    float m1 = -1e30f, m2 = -1e30f;
#pragma unroll
    for (int j = 0; j < 4; ++j) {
        if (v[j] > m1) { m2 = m1; m1 = v[j]; }
        else if (v[j] > m2) { m2 = v[j]; }
    }
#pragma unroll
    for (int d = 1; d <= 4; d <<= 1) {
        const float o1 = __shfl_xor(m1, d);
        const float o2 = __shfl_xor(m2, d);
        if (o1 > m1) { m2 = fmaxf(m1, o2); m1 = o1; }
        else         { m2 = fmaxf(m2, o1); }
    }
    const float gsum = m1 + m2;

    float gq[8];
#pragma unroll
    for (int g = 0; g < 8; ++g) gq[g] = __shfl(gsum, g * 8);
    int gm = 0;
    float g4v = -1e30f, gmargin = 1e30f;
#pragma unroll
    for (int rr = 0; rr < 5; ++rr) {
        int best = 0; float bv = -1e30f;
#pragma unroll
        for (int g = 0; g < 8; ++g) {
            const bool taken = (gm >> g) & 1;
            if (!taken && gq[g] > bv) { bv = gq[g]; best = g; }
        }
        if (rr < 4) { gm |= (1 << best); g4v = bv; }
        else gmargin = g4v - bv;
    }

    float cv[4];
    const bool inmask = (gm >> (lane >> 3)) & 1;
#pragma unroll
    for (int j = 0; j < 4; ++j) cv[j] = inmask ? v[j] : 0.0f;

    float wsum = 0.0f, my_w = 0.0f, prev = 0.0f, mmin = 1e30f;
    int my_i = 0;
#pragma unroll
    for (int rr = 0; rr < 9; ++rr) {
        float bv = cv[0]; int bj = 0;
#pragma unroll
        for (int j = 1; j < 4; ++j)
            if (cv[j] > bv) { bv = cv[j]; bj = j; }
        int bi = 4 * lane + bj;
        float braw = (bj == 0) ? raw[0] : (bj == 1) ? raw[1] : (bj == 2) ? raw[2] : raw[3];
#pragma unroll
        for (int d = 1; d < 64; d <<= 1) {
            const float ov  = __shfl_xor(bv, d);
            const int   oi  = __shfl_xor(bi, d);
            const float orw = __shfl_xor(braw, d);
            if (ov > bv || (ov == bv && oi < bi)) { bv = ov; bi = oi; braw = orw; }
        }
        if (rr > 0) mmin = fminf(mmin, prev - bv);
        prev = bv;
        if (rr < 8) {
            wsum += braw;
            if (lane == rr) { my_i = bi; my_w = braw; }
            if ((bi >> 2) == lane) cv[bi & 3] = -1e30f;
        }
    }

    const float scale = 2.5f / (wsum + 1e-20f);
    if (lane < 8) {
        out_idx[(size_t)t * 8 + lane] = (float)my_i;
        out_w [(size_t)t * 8 + lane] = my_w * scale;
    }
    const bool flag = (mmin < (float)MTAU) || (gmargin < (float)GTAU);
    if (flag && lane == 0) {
        const int idx = atomicAdd(cnt, 1);
        if (idx < RESCUE_CAP) list[idx] = t;
    }
}

// ---------------------------------------------------------------------------
// K4 v9: fp64 rescue GEMM, K-split x8 + single-barrier dbuf (round-4 proven).
// ---------------------------------------------------------------------------
__global__ __launch_bounds__(256, 2)
void rescue_gemm64_v9(const float* __restrict__ x, const float* __restrict__ w,
                      const int* __restrict__ cnt, const int* __restrict__ list,
                      double* __restrict__ resc /* [RESCUE_CAP][N_EXP] raw logits */)
{
    const int nf = min(*cnt, RESCUE_CAP);
    const int t0 = blockIdx.y * 32;
    if (t0 >= nf) return;

    __shared__ double xs[2][32][33];
    __shared__ double wsh[2][32][33];
    const int tid  = threadIdx.x;
    const int wave = tid >> 6;
    const int lane = tid & 63;
    const int e0 = blockIdx.x * 32;
    const int kbase = blockIdx.z * KR;
    const int la = lane & 15;
    const int kq = lane >> 4;

    const double p_idx = (kq == 0) ? (double)la : 0.0;
    const double p_one = (kq == 0) ? 1.0 : 0.0;
    f64x4 prow = (f64x4)(0.0), pcol = (f64x4)(0.0);
    prow = __builtin_amdgcn_mfma_f64_16x16x4f64(p_idx, p_one, prow, 0, 0, 0);
    pcol = __builtin_amdgcn_mfma_f64_16x16x4f64(p_one, p_idx, pcol, 0, 0, 0);
    int rrow[4], rcol[4];
#pragma unroll
    for (int i = 0; i < 4; ++i) {
        rrow[i] = (int)(prow[i] + 0.5);
        rcol[i] = (int)(pcol[i] + 0.5);
    }

    const int r = tid >> 3;     // 0..31
    const int q = tid & 7;
    const int tr = list[min(t0 + r, nf - 1)];
    const float* xp = x + (size_t)tr * HID + kbase + q * 4;
    const float* wp = w + (size_t)(e0 + r) * HID + kbase + q * 4;

    f64x4 acc = (f64x4)(0.0);
    const int m0 = (wave & 1) * 16;
    const int n0 = (wave >> 1) * 16;

    {
        const float4 xv = *(const float4*)xp;
        const float4 wv = *(const float4*)wp;
        const float a[4] = {xv.x, xv.y, xv.z, xv.w};
        const float b[4] = {wv.x, wv.y, wv.z, wv.w};
#pragma unroll
        for (int j = 0; j < 4; ++j) {
            xs[0][4 * q + j][r]  = (double)a[j];
            wsh[0][4 * q + j][r] = (double)b[j];
        }
    }
    __syncthreads();

    int cur = 0;
    for (int k0 = 0; k0 < KR; k0 += 32) {
        const int nxt = cur ^ 1;
        const bool more = (k0 + 32 < KR);
        float4 xv, wv;
        if (more) {
            xv = *(const float4*)(xp + k0 + 32);
            wv = *(const float4*)(wp + k0 + 32);
        }
#pragma unroll
        for (int s = 0; s < 8; ++s) {
            const int kk = s * 4 + kq;
            const double a = xs[cur][kk][m0 + la];
            const double b = wsh[cur][kk][n0 + la];
            acc = __builtin_amdgcn_mfma_f64_16x16x4f64(a, b, acc, 0, 0, 0);
        }
        if (more) {
            const float a[4] = {xv.x, xv.y, xv.z, xv.w};
            const float b[4] = {wv.x, wv.y, wv.z, wv.w};
#pragma unroll
            for (int j = 0; j < 4; ++j) {
                xs[nxt][4 * q + j][r]  = (double)a[j];
                wsh[nxt][4 * q + j][r] = (double)b[j];
            }
        }
        __syncthreads();
        cur = nxt;
    }

#pragma unroll
    for (int i = 0; i < 4; ++i) {
        const size_t lt = t0 + m0 + rrow[i];
        atomicAdd(&resc[lt * N_EXP + e0 + n0 + rcol[i]], acc[i]);
    }
}

// ---------------------------------------------------------------------------
// K5: fp64 rescue routing (sigmoid applied here; round-4 proven).
// ---------------------------------------------------------------------------
__global__ __launch_bounds__(256)
void rescue_route(const double* __restrict__ resc, const float* __restrict__ bias,
                  const int* __restrict__ cnt, const int* __restrict__ list,
                  float* __restrict__ out_idx, float* __restrict__ out_w)
{
    const int nf = min(*cnt, RESCUE_CAP);
    const int wave = threadIdx.x >> 6;
    const int lane = threadIdx.x & 63;
    const int i_tok = blockIdx.x * 4 + wave;
    if (i_tok >= nf) return;
    const int t = list[i_tok];
    const double* srow = resc + (size_t)i_tok * N_EXP;

    const float4 bf = *(const float4*)(bias + lane * 4);
    const float bfv[4] = {bf.x, bf.y, bf.z, bf.w};
    double raw[4], v[4];
#pragma unroll
    for (int j = 0; j < 4; ++j) {
        raw[j] = 1.0 / (1.0 + exp(-srow[4 * lane + j]));
        v[j] = raw[j] + (double)bfv[j];
    }

    double m1 = -1e300, m2 = -1e300;
#pragma unroll
    for (int j = 0; j < 4; ++j) {
        if (v[j] > m1) { m2 = m1; m1 = v[j]; }
        else if (v[j] > m2) { m2 = v[j]; }
    }
#pragma unroll
    for (int d = 1; d <= 4; d <<= 1) {
        const double o1 = __shfl_xor(m1, d);
        const double o2 = __shfl_xor(m2, d);
        if (o1 > m1) { m2 = fmax(m1, o2); m1 = o1; }
        else         { m2 = fmax(m2, o1); }
    }
    const double gsum = m1 + m2;

    double gq[8];
#pragma unroll
    for (int g = 0; g < 8; ++g) gq[g] = __shfl(gsum, g * 8);
    int gm = 0;
#pragma unroll
    for (int rr = 0; rr < 4; ++rr) {
        int best = 0; double bv = -1e300;
#pragma unroll
        for (int g = 0; g < 8; ++g) {
            const bool taken = (gm >> g) & 1;
            if (!taken && gq[g] > bv) { bv = gq[g]; best = g; }
        }
        gm |= (1 << best);
    }

    double cv[4];
    const bool inmask = (gm >> (lane >> 3)) & 1;
#pragma unroll
    for (int j = 0; j < 4; ++j) cv[j] = inmask ? v[j] : 0.0;

    double wsum = 0.0, my_w = 0.0;
    int my_i = 0;
#pragma unroll
    for (int rr = 0; rr < 8; ++rr) {
        double bv = cv[0]; int bj = 0;
#pragma unroll
        for (int j = 1; j < 4; ++j)
            if (cv[j] > bv) { bv = cv[j]; bj = j; }
        int bi = 4 * lane + bj;
        double braw = (bj == 0) ? raw[0] : (bj == 1) ? raw[1] : (bj == 2) ? raw[2] : raw[3];
#pragma unroll
        for (int d = 1; d < 64; d <<= 1) {
            const double ov  = __shfl_xor(bv, d);
            const int    oi  = __shfl_xor(bi, d);
            const double orw = __shfl_xor(braw, d);
            if (ov > bv || (ov == bv && oi < bi)) { bv = ov; bi = oi; braw = orw; }
        }
        wsum += braw;
        if (lane == rr) { my_i = bi; my_w = braw; }
        if ((bi >> 2) == lane) cv[bi & 3] = -1e300;
    }

    const double scale = 2.5 / (wsum + 1e-20);
    if (lane < 8) {
        out_idx[(size_t)t * 8 + lane] = (float)my_i;
        out_w [(size_t)t * 8 + lane] = (float)(my_w * scale);
    }
}

extern "C" void kernel_launch(void* const* d_in, const int* in_sizes, int n_in,
                              void* d_out, int out_size, void* d_ws, size_t ws_size,
                              hipStream_t stream)
{
    const float* x    = (const float*)d_in[0];
    const float* w    = (const float*)d_in[1];
    const float* bias = (const float*)d_in[2];
    float* out = (float*)d_out;

    char* ws = (char*)d_ws;
    float*  logits = (float*)ws;                       // 8,388,608 B
    double* resc   = (double*)ws;                      // alias: logits dead after route_flag
    u16*    wh     = (u16*)(ws + 8388608);             // 3,670,016 B (row-major)
    u16*    wl     = (u16*)(ws + 12058624);            // 3,670,016 B
    int*    cnt    = (int*)(ws + 15728640);
    int*    list   = (int*)(ws + 15728704);            // 2048*4

    prep<<<2048, 256, 0, stream>>>(w, wh, wl, logits, cnt);
    gemm_bf16split_v13<<<512, 256, 0, stream>>>(x, wh, wl, logits);
    route_flag<<<T_TOK / 4, 256, 0, stream>>>(logits, bias, out, out + (size_t)T_TOK * 8, cnt, list);
    // resc aliases logits -> zero AFTER route_flag consumed logits
    zero_resc<<<(RESCUE_CAP * N_EXP * 8) / (16 * 256), 256, 0, stream>>>((float4*)resc);
    rescue_gemm64_v9<<<dim3(N_EXP / 32, RESCUE_CAP / 32, HID / KR), 256, 0, stream>>>(x, w, cnt, list, resc);
    rescue_route<<<RESCUE_CAP / 4, 256, 0, stream>>>(resc, bias, cnt, list, out, out + (size_t)T_TOK * 8);
}